// Round 9
// baseline (106.274 us; speedup 1.0000x reference)
//
#include <hip/hip_runtime.h>

#define EPSILON 5.0f

constexpr int BLOCKS  = 2048;     // 8 blocks/CU on 256 CUs
constexpr int THREADS = 256;      // 4 waves/block

typedef float fx4 __attribute__((ext_vector_type(4)));

// Round 9 = round 8 with ONE change: feature loads are PLAIN (not nontemporal).
// A/B isolating NT: H1 (NT path less efficient) vs H2 (NT protects L2 for means).
// Everything else identical to round 8 (96.5 us).
__global__ __launch_bounds__(THREADS) void ncl_partial_kernel(
    const float* __restrict__ features,
    const float* __restrict__ means,
    const int* __restrict__ labels,
    float* __restrict__ partials,
    int B)
{
    const int lane = threadIdx.x & 63;
    const int gw = blockIdx.x * (THREADS >> 6) + (threadIdx.x >> 6);
    const int T = gridDim.x * (THREADS >> 6);
    const int nQ = B >> 2;                       // B divisible by 4 (262144)

    const fx4* __restrict__ F = reinterpret_cast<const fx4*>(features);
    const fx4* __restrict__ M = reinterpret_cast<const fx4*>(means);

    float wsum = 0.0f;   // meaningful on lane 0 only

    int q = gw;

    int c0 = 0, c1 = 0, c2 = 0, c3 = 0;
    if (q < nQ) {
        const int base = 4 * q;
        c0 = labels[base];     c1 = labels[base + 1];
        c2 = labels[base + 2]; c3 = labels[base + 3];
    }

    // prologue: features for current quad (plain loads)
    fx4 f00{0,0,0,0}, f01{0,0,0,0}, f10{0,0,0,0}, f11{0,0,0,0};
    fx4 f20{0,0,0,0}, f21{0,0,0,0}, f30{0,0,0,0}, f31{0,0,0,0};
    if (q < nQ) {
        const fx4* f0 = F + (size_t)(4 * q)     * 128;
        const fx4* f1 = F + (size_t)(4 * q + 1) * 128;
        const fx4* f2 = F + (size_t)(4 * q + 2) * 128;
        const fx4* f3 = F + (size_t)(4 * q + 3) * 128;
        f00 = f0[lane];      f01 = f0[lane + 64];
        f10 = f1[lane];      f11 = f1[lane + 64];
        f20 = f2[lane];      f21 = f2[lane + 64];
        f30 = f3[lane];      f31 = f3[lane + 64];
    }

    while (q < nQ) {
        const int nq = q + T;

        // ---- 1) prefetch next quad's features (8 plain loads, HBM) ----
        fx4 g00{0,0,0,0}, g01{0,0,0,0}, g10{0,0,0,0}, g11{0,0,0,0};
        fx4 g20{0,0,0,0}, g21{0,0,0,0}, g30{0,0,0,0}, g31{0,0,0,0};
        if (nq < nQ) {
            const fx4* f0 = F + (size_t)(4 * nq)     * 128;
            const fx4* f1 = F + (size_t)(4 * nq + 1) * 128;
            const fx4* f2 = F + (size_t)(4 * nq + 2) * 128;
            const fx4* f3 = F + (size_t)(4 * nq + 3) * 128;
            g00 = f0[lane];      g01 = f0[lane + 64];
            g10 = f1[lane];      g11 = f1[lane + 64];
            g20 = f2[lane];      g21 = f2[lane + 64];
            g30 = f3[lane];      g31 = f3[lane + 64];
        }

        // ---- 2) current quad's means (L2-resident; labels pre-resolved) ----
        const fx4* m0 = M + (size_t)c0 * 128;
        const fx4* m1 = M + (size_t)c1 * 128;
        const fx4* m2 = M + (size_t)c2 * 128;
        const fx4* m3 = M + (size_t)c3 * 128;
        const fx4 m00 = m0[lane], m01 = m0[lane + 64];
        const fx4 m10 = m1[lane], m11 = m1[lane + 64];
        const fx4 m20 = m2[lane], m21 = m2[lane + 64];
        const fx4 m30 = m3[lane], m31 = m3[lane + 64];

        // ---- 3) labels for next quad ----
        int d0 = 0, d1 = 0, d2 = 0, d3 = 0;
        if (nq < nQ) {
            const int base = 4 * nq;
            d0 = labels[base];     d1 = labels[base + 1];
            d2 = labels[base + 2]; d3 = labels[base + 3];
        }

        // ---- 4) compute current quad ----
        fx4 e, v0, v1, v2, v3;
        e = f00 - m00; v0 = e * e;  e = f01 - m01; v0 = e * e + v0;
        e = f10 - m10; v1 = e * e;  e = f11 - m11; v1 = e * e + v1;
        e = f20 - m20; v2 = e * e;  e = f21 - m21; v2 = e * e + v2;
        e = f30 - m30; v3 = e * e;  e = f31 - m31; v3 = e * e + v3;
        float a0 = (v0.x + v0.y) + (v0.z + v0.w);
        float a1 = (v1.x + v1.y) + (v1.z + v1.w);
        float a2 = (v2.x + v2.y) + (v2.z + v2.w);
        float a3 = (v3.x + v3.y) + (v3.z + v3.w);

        #pragma unroll
        for (int off = 32; off > 0; off >>= 1) {   // 4-wide ILP on DS pipe
            a0 += __shfl_xor(a0, off, 64);
            a1 += __shfl_xor(a1, off, 64);
            a2 += __shfl_xor(a2, off, 64);
            a3 += __shfl_xor(a3, off, 64);
        }

        if (lane == 0) {
            wsum += fmaxf(EPSILON - sqrtf(a0), 0.0f)
                  + fmaxf(EPSILON - sqrtf(a1), 0.0f)
                  + fmaxf(EPSILON - sqrtf(a2), 0.0f)
                  + fmaxf(EPSILON - sqrtf(a3), 0.0f);
        }

        // ---- 5) rotate pipeline ----
        f00 = g00; f01 = g01; f10 = g10; f11 = g11;
        f20 = g20; f21 = g21; f30 = g30; f31 = g31;
        c0 = d0; c1 = d1; c2 = d2; c3 = d3;
        q = nq;
    }

    __shared__ float s[THREADS >> 6];
    const int wv = threadIdx.x >> 6;
    if (lane == 0) s[wv] = wsum;
    __syncthreads();
    if (threadIdx.x == 0) {
        float t = 0.0f;
        #pragma unroll
        for (int i = 0; i < (THREADS >> 6); ++i) t += s[i];
        partials[blockIdx.x] = t;
    }
}

// Stage 2: single block reduces BLOCKS partials, writes mean.
__global__ __launch_bounds__(THREADS) void ncl_final_kernel(
    const float* __restrict__ partials,
    int n,
    float* __restrict__ out,
    float invB)
{
    float t = 0.0f;
    for (int i = threadIdx.x; i < n; i += THREADS) t += partials[i];

    #pragma unroll
    for (int off = 32; off > 0; off >>= 1)
        t += __shfl_xor(t, off, 64);

    __shared__ float s[THREADS >> 6];
    const int lane = threadIdx.x & 63;
    const int wv   = threadIdx.x >> 6;
    if (lane == 0) s[wv] = t;
    __syncthreads();
    if (threadIdx.x == 0) {
        float acc = 0.0f;
        #pragma unroll
        for (int i = 0; i < (THREADS >> 6); ++i) acc += s[i];
        out[0] = acc * invB;
    }
}

extern "C" void kernel_launch(void* const* d_in, const int* in_sizes, int n_in,
                              void* d_out, int out_size, void* d_ws, size_t ws_size,
                              hipStream_t stream) {
    const float* features = (const float*)d_in[0];
    const float* means    = (const float*)d_in[1];
    const int*   labels   = (const int*)d_in[2];
    float* out = (float*)d_out;

    const int B = in_sizes[2];        // one label per row
    float* partials = (float*)d_ws;   // BLOCKS floats

    ncl_partial_kernel<<<BLOCKS, THREADS, 0, stream>>>(features, means, labels,
                                                       partials, B);
    ncl_final_kernel<<<1, THREADS, 0, stream>>>(partials, BLOCKS, out,
                                                1.0f / (float)B);
}

// Round 10
// 96.339 us; speedup vs baseline: 1.1031x; 1.1031x over previous
//
#include <hip/hip_runtime.h>

#define EPSILON 5.0f

constexpr int BLOCKS  = 2048;     // 8 blocks/CU on 256 CUs
constexpr int THREADS = 256;      // 4 waves/block

typedef float fx4 __attribute__((ext_vector_type(4)));

// FINAL (= round 8, reverted after round-9 A/B).
// Key findings baked in:
//  - NT feature loads protect L2 residency of means: plain loads cost +10 us
//    (round-9 A/B). Features = streaming operand, means = cached operand.
//  - QUAD of rows per wave-iteration: 8 KiB features in flight per wave
//    through the whole compute phase (round 7->8: -2.7 us).
//  - Next quad's features issued at iteration TOP (full iteration to land);
//    means issued after (L2-resident, short latency); labels prefetched one
//    iteration ahead (no label->means chain in-loop).
//  - Two-kernel tail: fused threadfence/atomic tail regressed 2x (round 5).
__global__ __launch_bounds__(THREADS) void ncl_partial_kernel(
    const float* __restrict__ features,
    const float* __restrict__ means,
    const int* __restrict__ labels,
    float* __restrict__ partials,
    int B)
{
    const int lane = threadIdx.x & 63;
    const int gw = blockIdx.x * (THREADS >> 6) + (threadIdx.x >> 6);
    const int T = gridDim.x * (THREADS >> 6);
    const int nQ = B >> 2;                       // B divisible by 4 (262144)

    const fx4* __restrict__ F = reinterpret_cast<const fx4*>(features);
    const fx4* __restrict__ M = reinterpret_cast<const fx4*>(means);

    float wsum = 0.0f;   // meaningful on lane 0 only

    int q = gw;

    // labels for current quad (4 consecutive ints; mostly L1/L2 hits)
    int c0 = 0, c1 = 0, c2 = 0, c3 = 0;
    if (q < nQ) {
        const int base = 4 * q;
        c0 = labels[base];     c1 = labels[base + 1];
        c2 = labels[base + 2]; c3 = labels[base + 3];
    }

    // prologue: features for current quad
    fx4 f00{0,0,0,0}, f01{0,0,0,0}, f10{0,0,0,0}, f11{0,0,0,0};
    fx4 f20{0,0,0,0}, f21{0,0,0,0}, f30{0,0,0,0}, f31{0,0,0,0};
    if (q < nQ) {
        const fx4* f0 = F + (size_t)(4 * q)     * 128;
        const fx4* f1 = F + (size_t)(4 * q + 1) * 128;
        const fx4* f2 = F + (size_t)(4 * q + 2) * 128;
        const fx4* f3 = F + (size_t)(4 * q + 3) * 128;
        f00 = __builtin_nontemporal_load(f0 + lane);
        f01 = __builtin_nontemporal_load(f0 + lane + 64);
        f10 = __builtin_nontemporal_load(f1 + lane);
        f11 = __builtin_nontemporal_load(f1 + lane + 64);
        f20 = __builtin_nontemporal_load(f2 + lane);
        f21 = __builtin_nontemporal_load(f2 + lane + 64);
        f30 = __builtin_nontemporal_load(f3 + lane);
        f31 = __builtin_nontemporal_load(f3 + lane + 64);
    }

    while (q < nQ) {
        const int nq = q + T;

        // ---- 1) prefetch next quad's features (8 NT loads, HBM) ----
        fx4 g00{0,0,0,0}, g01{0,0,0,0}, g10{0,0,0,0}, g11{0,0,0,0};
        fx4 g20{0,0,0,0}, g21{0,0,0,0}, g30{0,0,0,0}, g31{0,0,0,0};
        if (nq < nQ) {
            const fx4* f0 = F + (size_t)(4 * nq)     * 128;
            const fx4* f1 = F + (size_t)(4 * nq + 1) * 128;
            const fx4* f2 = F + (size_t)(4 * nq + 2) * 128;
            const fx4* f3 = F + (size_t)(4 * nq + 3) * 128;
            g00 = __builtin_nontemporal_load(f0 + lane);
            g01 = __builtin_nontemporal_load(f0 + lane + 64);
            g10 = __builtin_nontemporal_load(f1 + lane);
            g11 = __builtin_nontemporal_load(f1 + lane + 64);
            g20 = __builtin_nontemporal_load(f2 + lane);
            g21 = __builtin_nontemporal_load(f2 + lane + 64);
            g30 = __builtin_nontemporal_load(f3 + lane);
            g31 = __builtin_nontemporal_load(f3 + lane + 64);
        }

        // ---- 2) current quad's means (L2-resident; labels pre-resolved) ----
        const fx4* m0 = M + (size_t)c0 * 128;
        const fx4* m1 = M + (size_t)c1 * 128;
        const fx4* m2 = M + (size_t)c2 * 128;
        const fx4* m3 = M + (size_t)c3 * 128;
        const fx4 m00 = m0[lane], m01 = m0[lane + 64];
        const fx4 m10 = m1[lane], m11 = m1[lane + 64];
        const fx4 m20 = m2[lane], m21 = m2[lane + 64];
        const fx4 m30 = m3[lane], m31 = m3[lane + 64];

        // ---- 3) labels for next quad ----
        int d0 = 0, d1 = 0, d2 = 0, d3 = 0;
        if (nq < nQ) {
            const int base = 4 * nq;
            d0 = labels[base];     d1 = labels[base + 1];
            d2 = labels[base + 2]; d3 = labels[base + 3];
        }

        // ---- 4) compute current quad ----
        fx4 e, v0, v1, v2, v3;
        e = f00 - m00; v0 = e * e;  e = f01 - m01; v0 = e * e + v0;
        e = f10 - m10; v1 = e * e;  e = f11 - m11; v1 = e * e + v1;
        e = f20 - m20; v2 = e * e;  e = f21 - m21; v2 = e * e + v2;
        e = f30 - m30; v3 = e * e;  e = f31 - m31; v3 = e * e + v3;
        float a0 = (v0.x + v0.y) + (v0.z + v0.w);
        float a1 = (v1.x + v1.y) + (v1.z + v1.w);
        float a2 = (v2.x + v2.y) + (v2.z + v2.w);
        float a3 = (v3.x + v3.y) + (v3.z + v3.w);

        #pragma unroll
        for (int off = 32; off > 0; off >>= 1) {   // 4-wide ILP on DS pipe
            a0 += __shfl_xor(a0, off, 64);
            a1 += __shfl_xor(a1, off, 64);
            a2 += __shfl_xor(a2, off, 64);
            a3 += __shfl_xor(a3, off, 64);
        }

        if (lane == 0) {
            wsum += fmaxf(EPSILON - sqrtf(a0), 0.0f)
                  + fmaxf(EPSILON - sqrtf(a1), 0.0f)
                  + fmaxf(EPSILON - sqrtf(a2), 0.0f)
                  + fmaxf(EPSILON - sqrtf(a3), 0.0f);
        }

        // ---- 5) rotate pipeline ----
        f00 = g00; f01 = g01; f10 = g10; f11 = g11;
        f20 = g20; f21 = g21; f30 = g30; f31 = g31;
        c0 = d0; c1 = d1; c2 = d2; c3 = d3;
        q = nq;
    }

    __shared__ float s[THREADS >> 6];
    const int wv = threadIdx.x >> 6;
    if (lane == 0) s[wv] = wsum;
    __syncthreads();
    if (threadIdx.x == 0) {
        float t = 0.0f;
        #pragma unroll
        for (int i = 0; i < (THREADS >> 6); ++i) t += s[i];
        partials[blockIdx.x] = t;
    }
}

// Stage 2: single block reduces BLOCKS partials, writes mean.
__global__ __launch_bounds__(THREADS) void ncl_final_kernel(
    const float* __restrict__ partials,
    int n,
    float* __restrict__ out,
    float invB)
{
    float t = 0.0f;
    for (int i = threadIdx.x; i < n; i += THREADS) t += partials[i];

    #pragma unroll
    for (int off = 32; off > 0; off >>= 1)
        t += __shfl_xor(t, off, 64);

    __shared__ float s[THREADS >> 6];
    const int lane = threadIdx.x & 63;
    const int wv   = threadIdx.x >> 6;
    if (lane == 0) s[wv] = t;
    __syncthreads();
    if (threadIdx.x == 0) {
        float acc = 0.0f;
        #pragma unroll
        for (int i = 0; i < (THREADS >> 6); ++i) acc += s[i];
        out[0] = acc * invB;
    }
}

extern "C" void kernel_launch(void* const* d_in, const int* in_sizes, int n_in,
                              void* d_out, int out_size, void* d_ws, size_t ws_size,
                              hipStream_t stream) {
    const float* features = (const float*)d_in[0];
    const float* means    = (const float*)d_in[1];
    const int*   labels   = (const int*)d_in[2];
    float* out = (float*)d_out;

    const int B = in_sizes[2];        // one label per row
    float* partials = (float*)d_ws;   // BLOCKS floats

    ncl_partial_kernel<<<BLOCKS, THREADS, 0, stream>>>(features, means, labels,
                                                       partials, B);
    ncl_final_kernel<<<1, THREADS, 0, stream>>>(partials, BLOCKS, out,
                                                1.0f / (float)B);
}